// Round 16
// baseline (343.446 us; speedup 1.0000x reference)
//
#include <hip/hip_runtime.h>
#include <hip/hip_bf16.h>
#include <math.h>
#include <stdint.h>

#define S_ 4096
#define H_ 1024
#define NH_ 16
#define HD_ 64
#define LOG2E 1.4426950408889634f
#define QSCALE (0.125f * LOG2E)

typedef __bf16 bf16;
typedef __attribute__((ext_vector_type(8))) __bf16 bf16x8;
typedef __attribute__((ext_vector_type(4))) __bf16 bf16x4;
typedef __attribute__((ext_vector_type(4))) float f32x4;
typedef __attribute__((ext_vector_type(16))) float f32x16;
typedef __attribute__((ext_vector_type(2))) float f32x2;
typedef __attribute__((ext_vector_type(2))) int int2v;

__device__ __forceinline__ f32x4 mfma16(bf16x8 a, bf16x8 b, f32x4 c) {
    return __builtin_amdgcn_mfma_f32_16x16x32_bf16(a, b, c, 0, 0, 0);
}
__device__ __forceinline__ f32x16 mfma32(bf16x8 a, bf16x8 b, f32x16 c) {
    return __builtin_amdgcn_mfma_f32_32x32x16_bf16(a, b, c, 0, 0, 0);
}

// async global->LDS, 16B per lane; LDS dest = wave-uniform base + lane*16.
__device__ __forceinline__ void gload16(const void* g, void* l) {
    __builtin_amdgcn_global_load_lds(
        (__attribute__((address_space(1))) void*)(uintptr_t)g,
        (__attribute__((address_space(3))) void*)(uintptr_t)l,
        16, 0, 0);
}

// pack two f32 -> one u32 of 2 bf16 (lo = a, hi = b) — proven r2
__device__ __forceinline__ unsigned cvtpk(float a, float b) {
    unsigned r;
    asm("v_cvt_pk_bf16_f32 %0, %1, %2" : "=v"(r) : "v"(a), "v"(b));
    return r;
}

// proven r2 half-wave exchange
__device__ __forceinline__ void swap32(unsigned a, unsigned b, unsigned& r0, unsigned& r1) {
#if __has_builtin(__builtin_amdgcn_permlane32_swap)
    int2v rr = __builtin_amdgcn_permlane32_swap((int)a, (int)b, false, false);
    r0 = (unsigned)rr[0];
    r1 = (unsigned)rr[1];
#else
    unsigned sa = (unsigned)__shfl_xor((int)a, 32, 64);
    unsigned sb = (unsigned)__shfl_xor((int)b, 32, 64);
    bool hi = (threadIdx.x & 32) != 0;
    r0 = hi ? sb : a;
    r1 = hi ? b : sa;
#endif
}

// raw hardware exp2: 1 instr (v_exp_f32). Inputs bounded ~|4| here.
__device__ __forceinline__ float fexp2(float x) {
#if __has_builtin(__builtin_amdgcn_exp2f)
    return __builtin_amdgcn_exp2f(x);
#else
    return exp2f(x);
#endif
}

// ---------------- fused cvt (all 4 tensors) + prep + counter zero ---------
__global__ __launch_bounds__(256) void cvt_all_kernel(
    const float* __restrict__ hs, const float* __restrict__ Wq,
    const float* __restrict__ Wk, const float* __restrict__ Wv,
    const float* __restrict__ mask,
    bf16* __restrict__ Xb, bf16* __restrict__ Wqb,
    bf16* __restrict__ Wkb, bf16* __restrict__ Wvb,
    float2* __restrict__ tab, bf16* __restrict__ wM, float* __restrict__ wV,
    int* __restrict__ cnt) {
    int b = blockIdx.x;
    const float* src; bf16* dst; size_t base;
    if (b < 2048)      { src = hs; dst = Xb;  base = (size_t)b * 2048; }
    else if (b < 2560) { src = Wq; dst = Wqb; base = (size_t)(b - 2048) * 2048; }
    else if (b < 3072) { src = Wk; dst = Wkb; base = (size_t)(b - 2560) * 2048; }
    else               { src = Wv; dst = Wvb; base = (size_t)(b - 3072) * 2048; }
    size_t i = base + threadIdx.x * 8;
    float4 v0 = *reinterpret_cast<const float4*>(src + i);
    float4 v1 = *reinterpret_cast<const float4*>(src + i + 4);
    bf16x8 o;
    o[0] = (bf16)v0.x; o[1] = (bf16)v0.y; o[2] = (bf16)v0.z; o[3] = (bf16)v0.w;
    o[4] = (bf16)v1.x; o[5] = (bf16)v1.y; o[6] = (bf16)v1.z; o[7] = (bf16)v1.w;
    *reinterpret_cast<bf16x8*>(dst + i) = o;

    int idx = b * 256 + threadIdx.x;
    if (idx < S_ * 32) {
        int ii = idx & 31, s = idx >> 5;
        double ang = (double)s * exp(-(double)(2 * ii) / 64.0 * log(10000.0));
        tab[idx] = make_float2((float)cos(ang), (float)sin(ang));
    }
    if (idx < S_) {
        float e = exp2f(mask[idx] * LOG2E);
        bf16 eb = (bf16)e;
        wM[idx] = eb;
        wV[idx] = (float)eb;
    }
    if (idx < NH_ * 32) cnt[idx] = 0;   // split-KV fixup flags
}

// ---------------- QKV GEMM + fused RoPE (Q,K) / mask-fold (V) epilogue ----
// (r10-proven, unchanged)
__global__ __launch_bounds__(256) void qkv_gemm_kernel(
    const bf16* __restrict__ Xb,
    const bf16* __restrict__ Wqb, const bf16* __restrict__ Wkb, const bf16* __restrict__ Wvb,
    const float* __restrict__ bqp, const float* __restrict__ bkp, const float* __restrict__ bvp,
    const float2* __restrict__ tab, const float* __restrict__ wV,
    bf16* __restrict__ Qo, bf16* __restrict__ Ko, bf16* __restrict__ Vto)
{
    __shared__ bf16 Alds[128 * 64];
    __shared__ bf16 Blds[128 * 64];
    const int z = blockIdx.z;
    const bf16* W = z == 0 ? Wqb : z == 1 ? Wkb : Wvb;
    const float* bias = z == 0 ? bqp : z == 1 ? bkp : bvp;
    const int tm = blockIdx.y * 128, tn = blockIdx.x * 128;
    const int tid = threadIdx.x, lane = tid & 63, wid = tid >> 6;
    const int wm = (wid >> 1) * 64, wn = (wid & 1) * 64;
    const int lr = lane & 15, lg = lane >> 4;
    const int c_row = tid >> 3, c_sub = tid & 7;

    f32x4 acc[4][4] = {};

    for (int kt = 0; kt < H_; kt += 64) {
        #pragma unroll
        for (int is = 0; is < 4; ++is) {
            int row = is * 32 + c_row;
            int sub = c_sub ^ (row & 7);
            gload16(&Xb[(size_t)(tm + row) * H_ + kt + sub * 8],
                    &Alds[(is * 256 + wid * 64) * 8]);
            gload16(&W[(size_t)(tn + row) * H_ + kt + sub * 8],
                    &Blds[(is * 256 + wid * 64) * 8]);
        }
        __syncthreads();

        #pragma unroll
        for (int kc = 0; kc < 2; ++kc) {
            bf16x8 af[4], bfr[4];
            #pragma unroll
            for (int mb = 0; mb < 4; ++mb) {
                int row = wm + mb * 16 + lr;
                int ch = (kc * 4 + lg) ^ (row & 7);
                af[mb] = *reinterpret_cast<const bf16x8*>(&Alds[row * 64 + ch * 8]);
            }
            #pragma unroll
            for (int nb = 0; nb < 4; ++nb) {
                int row = wn + nb * 16 + lr;
                int ch = (kc * 4 + lg) ^ (row & 7);
                bfr[nb] = *reinterpret_cast<const bf16x8*>(&Blds[row * 64 + ch * 8]);
            }
            #pragma unroll
            for (int mb = 0; mb < 4; ++mb)
                #pragma unroll
                for (int nb = 0; nb < 4; ++nb)
                    acc[mb][nb] = mfma16(af[mb], bfr[nb], acc[mb][nb]);
        }
        __syncthreads();
    }

    float bv4[4];
    #pragma unroll
    for (int nb = 0; nb < 4; ++nb) bv4[nb] = bias[tn + wn + nb * 16 + lr];

    if (z < 2) {
        bf16* Y = z == 0 ? Qo : Ko;
        const float fs = z == 0 ? QSCALE : 1.0f;
        #pragma unroll
        for (int mb = 0; mb < 4; ++mb) {
            #pragma unroll
            for (int r = 0; r < 4; ++r) {
                int row = tm + wm + mb * 16 + lg * 4 + r;
                #pragma unroll
                for (int nb = 0; nb < 2; ++nb) {
                    float2 cs = tab[row * 32 + nb * 16 + lr];
                    float x1 = acc[mb][nb][r] + bv4[nb];
                    float x2 = acc[mb][nb + 2][r] + bv4[nb + 2];
                    int col = tn + wn + nb * 16 + lr;
                    Y[(size_t)row * H_ + col]      = (bf16)((x1 * cs.x - x2 * cs.y) * fs);
                    Y[(size_t)row * H_ + col + 32] = (bf16)((x2 * cs.x + x1 * cs.y) * fs);
                }
            }
        }
    } else {
        #pragma unroll
        for (int mb = 0; mb < 4; ++mb) {
            int rowb = tm + wm + mb * 16 + lg * 4;   // key index base
            float4 wv = *reinterpret_cast<const float4*>(&wV[rowb]);
            float wvr[4] = {wv.x, wv.y, wv.z, wv.w};
            #pragma unroll
            for (int nb = 0; nb < 4; ++nb) {
                int col = tn + wn + nb * 16 + lr;
                bf16x4 pk;
                #pragma unroll
                for (int r = 0; r < 4; ++r)
                    pk[r] = (bf16)((acc[mb][nb][r] + bv4[nb]) * wvr[r]);
                *reinterpret_cast<bf16x4*>(&Vto[(size_t)col * S_ + rowb]) = pk;
            }
        }
    }
}

// ---------------- Flash attention: split-KV + XCD swizzle + fixup ---------
// r15-proven 64-VGPR serial body (4 waves/SIMD). New: (1) 1D grid with
// XCD-aware remap — xcd = id&7 hosts 4 (h,z) pairs, so each XCD's L2 holds
// only 2 heads' K/V/Q (~3 MB) and the fixup partner is XCD-local;
// (2) last-block fixup replaces the combine kernel: per-(h,x) atomic flag,
// second finisher reads the other partial (own still in regs), writes out.
template<int NSPLIT>
__global__ __launch_bounds__(256, 4) void attn_kernel(
    const bf16* __restrict__ Q, const bf16* __restrict__ K, const bf16* __restrict__ Vt,
    const bf16* __restrict__ wM, float* __restrict__ out,
    float* __restrict__ opart, float* __restrict__ lpart, int* __restrict__ cnt)
{
    __shared__ bf16 Kl[2][64 * 64];
    __shared__ bf16 Vl[2][64 * 64];
    __shared__ int finsh;
    int x, h, z;
    if (NSPLIT == 2) {
        int lin = blockIdx.x;                 // 1024 blocks, 1D
        int xcd = lin & 7, j = lin >> 3;      // id%8 -> XCD (heuristic remap)
        int pair = xcd + 8 * (j >> 5);        // 4 (h,z) pairs per XCD
        x = j & 31;
        h = pair & 15;
        z = pair >> 4;
    } else {
        x = blockIdx.x & 31;
        h = blockIdx.x >> 5;
        z = 0;
    }
    const int qb = x * 128;
    const int tid = threadIdx.x, lane = tid & 63, wid = tid >> 6;
    const int l31 = lane & 31, hi = lane >> 5;
    const int srow = wid * 8 + (lane >> 3);   // staging row (within 32-row group)
    const int ssub = (lane & 7) ^ (srow & 7); // swizzled chunk; (row+32)&7 == row&7

    const int NT = S_ / 64;
    const int t0 = z * (NT / NSPLIT), t1 = t0 + NT / NSPLIT;

    bf16x8 qf[4];
    {
        const bf16* qp = &Q[(size_t)(qb + wid * 32 + l31) * H_ + h * 64 + hi * 8];
        #pragma unroll
        for (int ks = 0; ks < 4; ++ks)
            qf[ks] = *reinterpret_cast<const bf16x8*>(qp + ks * 16);
    }

    f32x16 o0 = {}, o1 = {}, lacc = {};

    // running staging pointers, starting at tile t0
    const bf16* kg = &K[(size_t)(t0 * 64 + srow) * H_ + h * 64 + ssub * 8];
    const bf16* vg = &Vt[(size_t)(h * 64 + srow) * S_ + t0 * 64 + ssub * 8];

    auto STAGE = [&](int buf) {
        gload16(kg,           &Kl[buf][(wid * 8) * 64]);
        gload16(kg + 32 * H_, &Kl[buf][(32 + wid * 8) * 64]);
        gload16(vg,           &Vl[buf][(wid * 8) * 64]);
        gload16(vg + 32 * S_, &Vl[buf][(32 + wid * 8) * 64]);
        kg += 64 * H_;
        vg += 64;
    };

    STAGE(0);
    __syncthreads();
    int cur = 0;
    const bf16* wmt = wM + t0 * 64 + hi * 8;

    for (int t = t0; t < t1; ++t) {
        if (t + 1 < t1) STAGE(cur ^ 1);

        // ---- QK(t), serial ----
        f32x16 sc0 = {}, sc1 = {};
        const bf16* Kb_ = Kl[cur];
        __builtin_amdgcn_s_setprio(1);
        #pragma unroll
        for (int ks = 0; ks < 4; ++ks) {
            int ch = (2 * ks + hi) ^ (l31 & 7);
            bf16x8 kf0 = *reinterpret_cast<const bf16x8*>(&Kb_[l31 * 64 + ch * 8]);
            sc0 = mfma32(kf0, qf[ks], sc0);
            bf16x8 kf1 = *reinterpret_cast<const bf16x8*>(&Kb_[(32 + l31) * 64 + ch * 8]);
            sc1 = mfma32(kf1, qf[ks], sc1);
        }
        __builtin_amdgcn_s_setprio(0);

        // ---- softmax(t): p = exp2(score) in place (no mask, no max) ----
        #pragma unroll
        for (int r = 0; r < 16; ++r) sc0[r] = fexp2(sc0[r]);
        #pragma unroll
        for (int r = 0; r < 16; ++r) sc1[r] = fexp2(sc1[r]);

        // ---- P -> PV B-fragments (cvt_pk + permlane32_swap) ----
        bf16x8 pf[4];
        #pragma unroll
        for (int ks = 0; ks < 2; ++ks) {
            unsigned w[4];
            #pragma unroll
            for (int wi = 0; wi < 2; ++wi) {
                unsigned u = cvtpk(sc0[8 * ks + 2 * wi],     sc0[8 * ks + 2 * wi + 1]);
                unsigned v = cvtpk(sc0[8 * ks + 4 + 2 * wi], sc0[8 * ks + 4 + 2 * wi + 1]);
                swap32(u, v, w[wi], w[wi + 2]);
            }
            union { unsigned u[4]; bf16x8 v; } cv;
            cv.u[0] = w[0]; cv.u[1] = w[1]; cv.u[2] = w[2]; cv.u[3] = w[3];
            pf[ks] = cv.v;
        }
        #pragma unroll
        for (int ks = 0; ks < 2; ++ks) {
            unsigned w[4];
            #pragma unroll
            for (int wi = 0; wi < 2; ++wi) {
                unsigned u = cvtpk(sc1[8 * ks + 2 * wi],     sc1[8 * ks + 2 * wi + 1]);
                unsigned v = cvtpk(sc1[8 * ks + 4 + 2 * wi], sc1[8 * ks + 4 + 2 * wi + 1]);
                swap32(u, v, w[wi], w[wi + 2]);
            }
            union { unsigned u[4]; bf16x8 v; } cv;
            cv.u[0] = w[0]; cv.u[1] = w[1]; cv.u[2] = w[2]; cv.u[3] = w[3];
            pf[2 + ks] = cv.v;
        }

        // ---- PV(t) + l(t): O^T += Vt' * P^T ; lacc += wf * P^T ----
        const bf16* Vb_ = Vl[cur];
        __builtin_amdgcn_s_setprio(1);
        #pragma unroll
        for (int ks = 0; ks < 4; ++ks) {
            int ch = (2 * ks + hi) ^ (l31 & 7);
            bf16x8 vf0 = *reinterpret_cast<const bf16x8*>(&Vb_[l31 * 64 + ch * 8]);
            o0 = mfma32(vf0, pf[ks], o0);
            bf16x8 vf1 = *reinterpret_cast<const bf16x8*>(&Vb_[(32 + l31) * 64 + ch * 8]);
            o1 = mfma32(vf1, pf[ks], o1);
            bf16x8 wf = *reinterpret_cast<const bf16x8*>(wmt + ks * 16);
            lacc = mfma32(wf, pf[ks], lacc);
        }
        __builtin_amdgcn_s_setprio(0);
        wmt += 64;

        __syncthreads();
        cur ^= 1;
    }

    const int q = qb + wid * 32 + l31;
    if (NSPLIT == 1) {
        float inv = 1.f / lacc[0];
        float* orow = &out[(size_t)q * H_ + h * 64];
        #pragma unroll
        for (int g2 = 0; g2 < 4; ++g2) {
            float4 a, b;
            a.x = o0[g2 * 4 + 0] * inv; a.y = o0[g2 * 4 + 1] * inv;
            a.z = o0[g2 * 4 + 2] * inv; a.w = o0[g2 * 4 + 3] * inv;
            b.x = o1[g2 * 4 + 0] * inv; b.y = o1[g2 * 4 + 1] * inv;
            b.z = o1[g2 * 4 + 2] * inv; b.w = o1[g2 * 4 + 3] * inv;
            *reinterpret_cast<float4*>(orow + 8 * g2 + 4 * hi) = a;
            *reinterpret_cast<float4*>(orow + 32 + 8 * g2 + 4 * hi) = b;
        }
    } else {
        // ---- store my partial ----
        float* op = &opart[(((size_t)z * NH_ + h) * S_ + q) * 64];
        #pragma unroll
        for (int g2 = 0; g2 < 4; ++g2) {
            float4 a, b;
            a.x = o0[g2 * 4 + 0]; a.y = o0[g2 * 4 + 1];
            a.z = o0[g2 * 4 + 2]; a.w = o0[g2 * 4 + 3];
            b.x = o1[g2 * 4 + 0]; b.y = o1[g2 * 4 + 1];
            b.z = o1[g2 * 4 + 2]; b.w = o1[g2 * 4 + 3];
            *reinterpret_cast<float4*>(op + 8 * g2 + 4 * hi) = a;
            *reinterpret_cast<float4*>(op + 32 + 8 * g2 + 4 * hi) = b;
        }
        if (hi == 0)
            lpart[((size_t)z * NH_ + h) * S_ + q] = lacc[0];

        // ---- last-block fixup (CUDA threadfence-reduction pattern) ----
        __threadfence();                       // release my partial (agent)
        __syncthreads();                       // all threads fenced
        if (tid == 0)
            finsh = atomicAdd(&cnt[h * 32 + x], 1);   // device-scope [m20]
        __syncthreads();
        if (finsh == 1) {                      // I'm second: merge + write out
            __threadfence();                   // acquire other block's stores
            const int zo = 1 - z;
            const float* opo = &opart[(((size_t)zo * NH_ + h) * S_ + q) * 64];
            float lo_ = lpart[((size_t)zo * NH_ + h) * S_ + q];
            float inv = 1.f / (lacc[0] + lo_);
            float* orow = &out[(size_t)q * H_ + h * 64];
            #pragma unroll
            for (int g2 = 0; g2 < 4; ++g2) {
                float4 ao = *reinterpret_cast<const float4*>(opo + 8 * g2 + 4 * hi);
                float4 bo = *reinterpret_cast<const float4*>(opo + 32 + 8 * g2 + 4 * hi);
                float4 a, b;
                a.x = (o0[g2 * 4 + 0] + ao.x) * inv; a.y = (o0[g2 * 4 + 1] + ao.y) * inv;
                a.z = (o0[g2 * 4 + 2] + ao.z) * inv; a.w = (o0[g2 * 4 + 3] + ao.w) * inv;
                b.x = (o1[g2 * 4 + 0] + bo.x) * inv; b.y = (o1[g2 * 4 + 1] + bo.y) * inv;
                b.z = (o1[g2 * 4 + 2] + bo.z) * inv; b.w = (o1[g2 * 4 + 3] + bo.w) * inv;
                *reinterpret_cast<float4*>(orow + 8 * g2 + 4 * hi) = a;
                *reinterpret_cast<float4*>(orow + 32 + 8 * g2 + 4 * hi) = b;
            }
        }
    }
}

extern "C" void kernel_launch(void* const* d_in, const int* in_sizes, int n_in,
                              void* d_out, int out_size, void* d_ws, size_t ws_size,
                              hipStream_t stream) {
    const float* hs   = (const float*)d_in[0];
    const float* mask = (const float*)d_in[1];
    const float* Wq   = (const float*)d_in[2];
    const float* bq   = (const float*)d_in[3];
    const float* Wk   = (const float*)d_in[4];
    const float* bk   = (const float*)d_in[5];
    const float* Wv   = (const float*)d_in[6];
    const float* bv   = (const float*)d_in[7];
    float* out = (float*)d_out;

    char* ws = (char*)d_ws;
    bf16* Xb    = (bf16*)(ws);                  // 8 MB  [S,H]
    bf16* Wqb   = (bf16*)(ws + (8u  << 20));    // 2 MB
    bf16* Wkb   = (bf16*)(ws + (10u << 20));    // 2 MB
    bf16* Wvb   = (bf16*)(ws + (12u << 20));    // 2 MB
    bf16* Qb    = (bf16*)(ws + (14u << 20));    // 8 MB  [S,H]
    bf16* Kb    = (bf16*)(ws + (22u << 20));    // 8 MB  [S,H]
    bf16* Vt    = (bf16*)(ws + (30u << 20));    // 8 MB  [H,S]
    float2* tab = (float2*)(ws + (38u << 20));  // 1 MB  [S,32]
    bf16* wM    = (bf16*)(ws + (39u << 20));    // 8 KB  exp2-mask bf16
    float* wV   = (float*)(ws + (39u << 20) + 65536); // 16 KB exp2-mask f32
    float* opart = (float*)(ws + (40u << 20));  // 32 MB [2][NH][S][64]
    float* lpart = (float*)(ws + (72u << 20));  // 512 KB [2][NH][S]
    int*   cnt   = (int*)(ws + (72u << 20) + (512u << 10)); // 2 KB flags
    const size_t NEED = (size_t)73u << 20;

    cvt_all_kernel<<<3584, 256, 0, stream>>>(hs, Wq, Wk, Wv, mask,
                                             Xb, Wqb, Wkb, Wvb, tab, wM, wV, cnt);
    qkv_gemm_kernel<<<dim3(H_ / 128, S_ / 128, 3), 256, 0, stream>>>(
        Xb, Wqb, Wkb, Wvb, bq, bk, bv, tab, wV, Qb, Kb, Vt);

    if (ws_size >= NEED) {
        attn_kernel<2><<<1024, 256, 0, stream>>>(
            Qb, Kb, Vt, wM, out, opart, lpart, cnt);
    } else {
        attn_kernel<1><<<512, 256, 0, stream>>>(
            Qb, Kb, Vt, wM, out, nullptr, nullptr, nullptr);
    }
}

// Round 17
// 154.344 us; speedup vs baseline: 2.2252x; 2.2252x over previous
//
#include <hip/hip_runtime.h>
#include <hip/hip_bf16.h>
#include <math.h>
#include <stdint.h>

#define S_ 4096
#define H_ 1024
#define NH_ 16
#define HD_ 64
#define LOG2E 1.4426950408889634f
#define QSCALE (0.125f * LOG2E)

typedef __bf16 bf16;
typedef __attribute__((ext_vector_type(8))) __bf16 bf16x8;
typedef __attribute__((ext_vector_type(4))) __bf16 bf16x4;
typedef __attribute__((ext_vector_type(4))) float f32x4;
typedef __attribute__((ext_vector_type(16))) float f32x16;
typedef __attribute__((ext_vector_type(2))) float f32x2;
typedef __attribute__((ext_vector_type(2))) int int2v;

__device__ __forceinline__ f32x4 mfma16(bf16x8 a, bf16x8 b, f32x4 c) {
    return __builtin_amdgcn_mfma_f32_16x16x32_bf16(a, b, c, 0, 0, 0);
}
__device__ __forceinline__ f32x16 mfma32(bf16x8 a, bf16x8 b, f32x16 c) {
    return __builtin_amdgcn_mfma_f32_32x32x16_bf16(a, b, c, 0, 0, 0);
}

// async global->LDS, 16B per lane; LDS dest = wave-uniform base + lane*16.
__device__ __forceinline__ void gload16(const void* g, void* l) {
    __builtin_amdgcn_global_load_lds(
        (__attribute__((address_space(1))) void*)(uintptr_t)g,
        (__attribute__((address_space(3))) void*)(uintptr_t)l,
        16, 0, 0);
}

// pack two f32 -> one u32 of 2 bf16 (lo = a, hi = b) — proven r2
__device__ __forceinline__ unsigned cvtpk(float a, float b) {
    unsigned r;
    asm("v_cvt_pk_bf16_f32 %0, %1, %2" : "=v"(r) : "v"(a), "v"(b));
    return r;
}

// proven r2 half-wave exchange
__device__ __forceinline__ void swap32(unsigned a, unsigned b, unsigned& r0, unsigned& r1) {
#if __has_builtin(__builtin_amdgcn_permlane32_swap)
    int2v rr = __builtin_amdgcn_permlane32_swap((int)a, (int)b, false, false);
    r0 = (unsigned)rr[0];
    r1 = (unsigned)rr[1];
#else
    unsigned sa = (unsigned)__shfl_xor((int)a, 32, 64);
    unsigned sb = (unsigned)__shfl_xor((int)b, 32, 64);
    bool hi = (threadIdx.x & 32) != 0;
    r0 = hi ? sb : a;
    r1 = hi ? b : sa;
#endif
}

// raw hardware exp2: 1 instr (v_exp_f32). Inputs bounded ~|4| here.
__device__ __forceinline__ float fexp2(float x) {
#if __has_builtin(__builtin_amdgcn_exp2f)
    return __builtin_amdgcn_exp2f(x);
#else
    return exp2f(x);
#endif
}

// ---------------- fused cvt (all 4 tensors) + prep (rope table, exp2 mask)
__global__ __launch_bounds__(256) void cvt_all_kernel(
    const float* __restrict__ hs, const float* __restrict__ Wq,
    const float* __restrict__ Wk, const float* __restrict__ Wv,
    const float* __restrict__ mask,
    bf16* __restrict__ Xb, bf16* __restrict__ Wqb,
    bf16* __restrict__ Wkb, bf16* __restrict__ Wvb,
    float2* __restrict__ tab, bf16* __restrict__ wM, float* __restrict__ wV) {
    int b = blockIdx.x;
    const float* src; bf16* dst; size_t base;
    if (b < 2048)      { src = hs; dst = Xb;  base = (size_t)b * 2048; }
    else if (b < 2560) { src = Wq; dst = Wqb; base = (size_t)(b - 2048) * 2048; }
    else if (b < 3072) { src = Wk; dst = Wkb; base = (size_t)(b - 2560) * 2048; }
    else               { src = Wv; dst = Wvb; base = (size_t)(b - 3072) * 2048; }
    size_t i = base + threadIdx.x * 8;
    float4 v0 = *reinterpret_cast<const float4*>(src + i);
    float4 v1 = *reinterpret_cast<const float4*>(src + i + 4);
    bf16x8 o;
    o[0] = (bf16)v0.x; o[1] = (bf16)v0.y; o[2] = (bf16)v0.z; o[3] = (bf16)v0.w;
    o[4] = (bf16)v1.x; o[5] = (bf16)v1.y; o[6] = (bf16)v1.z; o[7] = (bf16)v1.w;
    *reinterpret_cast<bf16x8*>(dst + i) = o;

    int idx = b * 256 + threadIdx.x;
    if (idx < S_ * 32) {
        int ii = idx & 31, s = idx >> 5;
        double ang = (double)s * exp(-(double)(2 * ii) / 64.0 * log(10000.0));
        tab[idx] = make_float2((float)cos(ang), (float)sin(ang));
    }
    if (idx < S_) {
        float e = exp2f(mask[idx] * LOG2E);
        bf16 eb = (bf16)e;
        wM[idx] = eb;
        wV[idx] = (float)eb;
    }
}

// ---------------- QKV GEMM + fused RoPE (Q,K) / mask-fold (V) epilogue ----
// (r10-proven, unchanged)
__global__ __launch_bounds__(256) void qkv_gemm_kernel(
    const bf16* __restrict__ Xb,
    const bf16* __restrict__ Wqb, const bf16* __restrict__ Wkb, const bf16* __restrict__ Wvb,
    const float* __restrict__ bqp, const float* __restrict__ bkp, const float* __restrict__ bvp,
    const float2* __restrict__ tab, const float* __restrict__ wV,
    bf16* __restrict__ Qo, bf16* __restrict__ Ko, bf16* __restrict__ Vto)
{
    __shared__ bf16 Alds[128 * 64];
    __shared__ bf16 Blds[128 * 64];
    const int z = blockIdx.z;
    const bf16* W = z == 0 ? Wqb : z == 1 ? Wkb : Wvb;
    const float* bias = z == 0 ? bqp : z == 1 ? bkp : bvp;
    const int tm = blockIdx.y * 128, tn = blockIdx.x * 128;
    const int tid = threadIdx.x, lane = tid & 63, wid = tid >> 6;
    const int wm = (wid >> 1) * 64, wn = (wid & 1) * 64;
    const int lr = lane & 15, lg = lane >> 4;
    const int c_row = tid >> 3, c_sub = tid & 7;

    f32x4 acc[4][4] = {};

    for (int kt = 0; kt < H_; kt += 64) {
        #pragma unroll
        for (int is = 0; is < 4; ++is) {
            int row = is * 32 + c_row;
            int sub = c_sub ^ (row & 7);
            gload16(&Xb[(size_t)(tm + row) * H_ + kt + sub * 8],
                    &Alds[(is * 256 + wid * 64) * 8]);
            gload16(&W[(size_t)(tn + row) * H_ + kt + sub * 8],
                    &Blds[(is * 256 + wid * 64) * 8]);
        }
        __syncthreads();

        #pragma unroll
        for (int kc = 0; kc < 2; ++kc) {
            bf16x8 af[4], bfr[4];
            #pragma unroll
            for (int mb = 0; mb < 4; ++mb) {
                int row = wm + mb * 16 + lr;
                int ch = (kc * 4 + lg) ^ (row & 7);
                af[mb] = *reinterpret_cast<const bf16x8*>(&Alds[row * 64 + ch * 8]);
            }
            #pragma unroll
            for (int nb = 0; nb < 4; ++nb) {
                int row = wn + nb * 16 + lr;
                int ch = (kc * 4 + lg) ^ (row & 7);
                bfr[nb] = *reinterpret_cast<const bf16x8*>(&Blds[row * 64 + ch * 8]);
            }
            #pragma unroll
            for (int mb = 0; mb < 4; ++mb)
                #pragma unroll
                for (int nb = 0; nb < 4; ++nb)
                    acc[mb][nb] = mfma16(af[mb], bfr[nb], acc[mb][nb]);
        }
        __syncthreads();
    }

    float bv4[4];
    #pragma unroll
    for (int nb = 0; nb < 4; ++nb) bv4[nb] = bias[tn + wn + nb * 16 + lr];

    if (z < 2) {
        bf16* Y = z == 0 ? Qo : Ko;
        const float fs = z == 0 ? QSCALE : 1.0f;
        #pragma unroll
        for (int mb = 0; mb < 4; ++mb) {
            #pragma unroll
            for (int r = 0; r < 4; ++r) {
                int row = tm + wm + mb * 16 + lg * 4 + r;
                #pragma unroll
                for (int nb = 0; nb < 2; ++nb) {
                    float2 cs = tab[row * 32 + nb * 16 + lr];
                    float x1 = acc[mb][nb][r] + bv4[nb];
                    float x2 = acc[mb][nb + 2][r] + bv4[nb + 2];
                    int col = tn + wn + nb * 16 + lr;
                    Y[(size_t)row * H_ + col]      = (bf16)((x1 * cs.x - x2 * cs.y) * fs);
                    Y[(size_t)row * H_ + col + 32] = (bf16)((x2 * cs.x + x1 * cs.y) * fs);
                }
            }
        }
    } else {
        #pragma unroll
        for (int mb = 0; mb < 4; ++mb) {
            int rowb = tm + wm + mb * 16 + lg * 4;   // key index base
            float4 wv = *reinterpret_cast<const float4*>(&wV[rowb]);
            float wvr[4] = {wv.x, wv.y, wv.z, wv.w};
            #pragma unroll
            for (int nb = 0; nb < 4; ++nb) {
                int col = tn + wn + nb * 16 + lr;
                bf16x4 pk;
                #pragma unroll
                for (int r = 0; r < 4; ++r)
                    pk[r] = (bf16)((acc[mb][nb][r] + bv4[nb]) * wvr[r]);
                *reinterpret_cast<bf16x4*>(&Vto[(size_t)col * S_ + rowb]) = pk;
            }
        }
    }
}

// ---------------- Flash attention: split-KV + XCD swizzle (no fence) ------
// r15-proven 64-VGPR serial body, 4 waves/SIMD. Only delta vs r15: the
// NSPLIT=2 grid is 1D with an XCD-aware remap (r16-proven mechanism:
// FETCH 69.8 -> 21.7 MB) — xcd = id&7 hosts 4 (h,z) pairs, so each XCD's
// L2 holds only 2 heads' K/V/Q (~3 MB). Partials merged by the separate
// combine kernel (kernel boundary = the device-scope release; NO
// __threadfence — r16 showed it L2-writebacks every block, 3x regression).
template<int NSPLIT>
__global__ __launch_bounds__(256, 4) void attn_kernel(
    const bf16* __restrict__ Q, const bf16* __restrict__ K, const bf16* __restrict__ Vt,
    const bf16* __restrict__ wM, float* __restrict__ out,
    float* __restrict__ opart, float* __restrict__ lpart)
{
    __shared__ bf16 Kl[2][64 * 64];
    __shared__ bf16 Vl[2][64 * 64];
    int x, h, z;
    if (NSPLIT == 2) {
        int lin = blockIdx.x;                 // 1024 blocks, 1D
        int xcd = lin & 7, j = lin >> 3;      // id%8 -> XCD (default round-robin)
        int pair = xcd + 8 * (j >> 5);        // 4 (h,z) pairs per XCD
        x = j & 31;
        h = pair & 15;
        z = pair >> 4;
    } else {
        x = blockIdx.x;
        h = blockIdx.y;
        z = 0;
    }
    const int qb = x * 128;
    const int tid = threadIdx.x, lane = tid & 63, wid = tid >> 6;
    const int l31 = lane & 31, hi = lane >> 5;
    const int srow = wid * 8 + (lane >> 3);   // staging row (within 32-row group)
    const int ssub = (lane & 7) ^ (srow & 7); // swizzled chunk; (row+32)&7 == row&7

    const int NT = S_ / 64;
    const int t0 = z * (NT / NSPLIT), t1 = t0 + NT / NSPLIT;

    bf16x8 qf[4];
    {
        const bf16* qp = &Q[(size_t)(qb + wid * 32 + l31) * H_ + h * 64 + hi * 8];
        #pragma unroll
        for (int ks = 0; ks < 4; ++ks)
            qf[ks] = *reinterpret_cast<const bf16x8*>(qp + ks * 16);
    }

    f32x16 o0 = {}, o1 = {}, lacc = {};

    // running staging pointers, starting at tile t0
    const bf16* kg = &K[(size_t)(t0 * 64 + srow) * H_ + h * 64 + ssub * 8];
    const bf16* vg = &Vt[(size_t)(h * 64 + srow) * S_ + t0 * 64 + ssub * 8];

    auto STAGE = [&](int buf) {
        gload16(kg,           &Kl[buf][(wid * 8) * 64]);
        gload16(kg + 32 * H_, &Kl[buf][(32 + wid * 8) * 64]);
        gload16(vg,           &Vl[buf][(wid * 8) * 64]);
        gload16(vg + 32 * S_, &Vl[buf][(32 + wid * 8) * 64]);
        kg += 64 * H_;
        vg += 64;
    };

    STAGE(0);
    __syncthreads();
    int cur = 0;
    const bf16* wmt = wM + t0 * 64 + hi * 8;

    for (int t = t0; t < t1; ++t) {
        if (t + 1 < t1) STAGE(cur ^ 1);

        // ---- QK(t), serial ----
        f32x16 sc0 = {}, sc1 = {};
        const bf16* Kb_ = Kl[cur];
        __builtin_amdgcn_s_setprio(1);
        #pragma unroll
        for (int ks = 0; ks < 4; ++ks) {
            int ch = (2 * ks + hi) ^ (l31 & 7);
            bf16x8 kf0 = *reinterpret_cast<const bf16x8*>(&Kb_[l31 * 64 + ch * 8]);
            sc0 = mfma32(kf0, qf[ks], sc0);
            bf16x8 kf1 = *reinterpret_cast<const bf16x8*>(&Kb_[(32 + l31) * 64 + ch * 8]);
            sc1 = mfma32(kf1, qf[ks], sc1);
        }
        __builtin_amdgcn_s_setprio(0);

        // ---- softmax(t): p = exp2(score) in place (no mask, no max) ----
        #pragma unroll
        for (int r = 0; r < 16; ++r) sc0[r] = fexp2(sc0[r]);
        #pragma unroll
        for (int r = 0; r < 16; ++r) sc1[r] = fexp2(sc1[r]);

        // ---- P -> PV B-fragments (cvt_pk + permlane32_swap) ----
        bf16x8 pf[4];
        #pragma unroll
        for (int ks = 0; ks < 2; ++ks) {
            unsigned w[4];
            #pragma unroll
            for (int wi = 0; wi < 2; ++wi) {
                unsigned u = cvtpk(sc0[8 * ks + 2 * wi],     sc0[8 * ks + 2 * wi + 1]);
                unsigned v = cvtpk(sc0[8 * ks + 4 + 2 * wi], sc0[8 * ks + 4 + 2 * wi + 1]);
                swap32(u, v, w[wi], w[wi + 2]);
            }
            union { unsigned u[4]; bf16x8 v; } cv;
            cv.u[0] = w[0]; cv.u[1] = w[1]; cv.u[2] = w[2]; cv.u[3] = w[3];
            pf[ks] = cv.v;
        }
        #pragma unroll
        for (int ks = 0; ks < 2; ++ks) {
            unsigned w[4];
            #pragma unroll
            for (int wi = 0; wi < 2; ++wi) {
                unsigned u = cvtpk(sc1[8 * ks + 2 * wi],     sc1[8 * ks + 2 * wi + 1]);
                unsigned v = cvtpk(sc1[8 * ks + 4 + 2 * wi], sc1[8 * ks + 4 + 2 * wi + 1]);
                swap32(u, v, w[wi], w[wi + 2]);
            }
            union { unsigned u[4]; bf16x8 v; } cv;
            cv.u[0] = w[0]; cv.u[1] = w[1]; cv.u[2] = w[2]; cv.u[3] = w[3];
            pf[2 + ks] = cv.v;
        }

        // ---- PV(t) + l(t): O^T += Vt' * P^T ; lacc += wf * P^T ----
        const bf16* Vb_ = Vl[cur];
        __builtin_amdgcn_s_setprio(1);
        #pragma unroll
        for (int ks = 0; ks < 4; ++ks) {
            int ch = (2 * ks + hi) ^ (l31 & 7);
            bf16x8 vf0 = *reinterpret_cast<const bf16x8*>(&Vb_[l31 * 64 + ch * 8]);
            o0 = mfma32(vf0, pf[ks], o0);
            bf16x8 vf1 = *reinterpret_cast<const bf16x8*>(&Vb_[(32 + l31) * 64 + ch * 8]);
            o1 = mfma32(vf1, pf[ks], o1);
            bf16x8 wf = *reinterpret_cast<const bf16x8*>(wmt + ks * 16);
            lacc = mfma32(wf, pf[ks], lacc);
        }
        __builtin_amdgcn_s_setprio(0);
        wmt += 64;

        __syncthreads();
        cur ^= 1;
    }

    const int q = qb + wid * 32 + l31;
    if (NSPLIT == 1) {
        float inv = 1.f / lacc[0];
        float* orow = &out[(size_t)q * H_ + h * 64];
        #pragma unroll
        for (int g2 = 0; g2 < 4; ++g2) {
            float4 a, b;
            a.x = o0[g2 * 4 + 0] * inv; a.y = o0[g2 * 4 + 1] * inv;
            a.z = o0[g2 * 4 + 2] * inv; a.w = o0[g2 * 4 + 3] * inv;
            b.x = o1[g2 * 4 + 0] * inv; b.y = o1[g2 * 4 + 1] * inv;
            b.z = o1[g2 * 4 + 2] * inv; b.w = o1[g2 * 4 + 3] * inv;
            *reinterpret_cast<float4*>(orow + 8 * g2 + 4 * hi) = a;
            *reinterpret_cast<float4*>(orow + 32 + 8 * g2 + 4 * hi) = b;
        }
    } else {
        float* op = &opart[(((size_t)z * NH_ + h) * S_ + q) * 64];
        #pragma unroll
        for (int g2 = 0; g2 < 4; ++g2) {
            float4 a, b;
            a.x = o0[g2 * 4 + 0]; a.y = o0[g2 * 4 + 1];
            a.z = o0[g2 * 4 + 2]; a.w = o0[g2 * 4 + 3];
            b.x = o1[g2 * 4 + 0]; b.y = o1[g2 * 4 + 1];
            b.z = o1[g2 * 4 + 2]; b.w = o1[g2 * 4 + 3];
            *reinterpret_cast<float4*>(op + 8 * g2 + 4 * hi) = a;
            *reinterpret_cast<float4*>(op + 32 + 8 * g2 + 4 * hi) = b;
        }
        if (hi == 0)
            lpart[((size_t)z * NH_ + h) * S_ + q] = lacc[0];
    }
}

// ---------------- combine the two KV-half partials (fixed-max: just sums) -
__global__ __launch_bounds__(256) void combine_kernel(const float* __restrict__ opart,
                                                      const float* __restrict__ lpart,
                                                      float* __restrict__ out) {
    int idx = blockIdx.x * 256 + threadIdx.x;   // 2^20 threads, float4 each
    int d4 = idx & 15;
    int q = (idx >> 4) & 4095;
    int h = idx >> 16;
    float l0 = lpart[(size_t)h * S_ + q];
    float l1 = lpart[((size_t)NH_ + h) * S_ + q];
    float inv = 1.f / (l0 + l1);
    float4 a = *reinterpret_cast<const float4*>(&opart[(((size_t)h) * S_ + q) * 64 + d4 * 4]);
    float4 b = *reinterpret_cast<const float4*>(&opart[(((size_t)NH_ + h) * S_ + q) * 64 + d4 * 4]);
    float4 r;
    r.x = (a.x + b.x) * inv;
    r.y = (a.y + b.y) * inv;
    r.z = (a.z + b.z) * inv;
    r.w = (a.w + b.w) * inv;
    *reinterpret_cast<float4*>(&out[(size_t)q * H_ + h * 64 + d4 * 4]) = r;
}

extern "C" void kernel_launch(void* const* d_in, const int* in_sizes, int n_in,
                              void* d_out, int out_size, void* d_ws, size_t ws_size,
                              hipStream_t stream) {
    const float* hs   = (const float*)d_in[0];
    const float* mask = (const float*)d_in[1];
    const float* Wq   = (const float*)d_in[2];
    const float* bq   = (const float*)d_in[3];
    const float* Wk   = (const float*)d_in[4];
    const float* bk   = (const float*)d_in[5];
    const float* Wv   = (const float*)d_in[6];
    const float* bv   = (const float*)d_in[7];
    float* out = (float*)d_out;

    char* ws = (char*)d_ws;
    bf16* Xb    = (bf16*)(ws);                  // 8 MB  [S,H]
    bf16* Wqb   = (bf16*)(ws + (8u  << 20));    // 2 MB
    bf16* Wkb   = (bf16*)(ws + (10u << 20));    // 2 MB
    bf16* Wvb   = (bf16*)(ws + (12u << 20));    // 2 MB
    bf16* Qb    = (bf16*)(ws + (14u << 20));    // 8 MB  [S,H]
    bf16* Kb    = (bf16*)(ws + (22u << 20));    // 8 MB  [S,H]
    bf16* Vt    = (bf16*)(ws + (30u << 20));    // 8 MB  [H,S]
    float2* tab = (float2*)(ws + (38u << 20));  // 1 MB  [S,32]
    bf16* wM    = (bf16*)(ws + (39u << 20));    // 8 KB  exp2-mask bf16
    float* wV   = (float*)(ws + (39u << 20) + 65536); // 16 KB exp2-mask f32
    float* opart = (float*)(ws + (40u << 20));  // 32 MB [2][NH][S][64]
    float* lpart = (float*)(ws + (72u << 20));  // 512 KB [2][NH][S]
    const size_t NEED = (size_t)73u << 20;

    cvt_all_kernel<<<3584, 256, 0, stream>>>(hs, Wq, Wk, Wv, mask,
                                             Xb, Wqb, Wkb, Wvb, tab, wM, wV);
    qkv_gemm_kernel<<<dim3(H_ / 128, S_ / 128, 3), 256, 0, stream>>>(
        Xb, Wqb, Wkb, Wvb, bq, bk, bv, tab, wV, Qb, Kb, Vt);

    if (ws_size >= NEED) {
        attn_kernel<2><<<1024, 256, 0, stream>>>(
            Qb, Kb, Vt, wM, out, opart, lpart);
        combine_kernel<<<(S_ * NH_ * 16) / 256, 256, 0, stream>>>(opart, lpart, out);
    } else {
        attn_kernel<1><<<dim3(S_ / 128, NH_, 1), 256, 0, stream>>>(
            Qb, Kb, Vt, wM, out, nullptr, nullptr);
    }
}

// Round 18
// 141.444 us; speedup vs baseline: 2.4281x; 1.0912x over previous
//
#include <hip/hip_runtime.h>
#include <hip/hip_bf16.h>
#include <math.h>
#include <stdint.h>

#define S_ 4096
#define H_ 1024
#define NH_ 16
#define HD_ 64
#define LOG2E 1.4426950408889634f
#define QSCALE (0.125f * LOG2E)

typedef __bf16 bf16;
typedef __attribute__((ext_vector_type(8))) __bf16 bf16x8;
typedef __attribute__((ext_vector_type(4))) __bf16 bf16x4;
typedef __attribute__((ext_vector_type(4))) float f32x4;
typedef __attribute__((ext_vector_type(16))) float f32x16;
typedef __attribute__((ext_vector_type(2))) float f32x2;
typedef __attribute__((ext_vector_type(2))) int int2v;

__device__ __forceinline__ f32x4 mfma16(bf16x8 a, bf16x8 b, f32x4 c) {
    return __builtin_amdgcn_mfma_f32_16x16x32_bf16(a, b, c, 0, 0, 0);
}
__device__ __forceinline__ f32x16 mfma32(bf16x8 a, bf16x8 b, f32x16 c) {
    return __builtin_amdgcn_mfma_f32_32x32x16_bf16(a, b, c, 0, 0, 0);
}

// async global->LDS, 16B per lane; LDS dest = wave-uniform base + lane*16.
__device__ __forceinline__ void gload16(const void* g, void* l) {
    __builtin_amdgcn_global_load_lds(
        (__attribute__((address_space(1))) void*)(uintptr_t)g,
        (__attribute__((address_space(3))) void*)(uintptr_t)l,
        16, 0, 0);
}

// pack two f32 -> one u32 of 2 bf16 (lo = a, hi = b) — proven r2
__device__ __forceinline__ unsigned cvtpk(float a, float b) {
    unsigned r;
    asm("v_cvt_pk_bf16_f32 %0, %1, %2" : "=v"(r) : "v"(a), "v"(b));
    return r;
}

// proven r2 half-wave exchange
__device__ __forceinline__ void swap32(unsigned a, unsigned b, unsigned& r0, unsigned& r1) {
#if __has_builtin(__builtin_amdgcn_permlane32_swap)
    int2v rr = __builtin_amdgcn_permlane32_swap((int)a, (int)b, false, false);
    r0 = (unsigned)rr[0];
    r1 = (unsigned)rr[1];
#else
    unsigned sa = (unsigned)__shfl_xor((int)a, 32, 64);
    unsigned sb = (unsigned)__shfl_xor((int)b, 32, 64);
    bool hi = (threadIdx.x & 32) != 0;
    r0 = hi ? sb : a;
    r1 = hi ? b : sa;
#endif
}

// raw hardware exp2: 1 instr (v_exp_f32). Inputs bounded ~|4| here.
__device__ __forceinline__ float fexp2(float x) {
#if __has_builtin(__builtin_amdgcn_exp2f)
    return __builtin_amdgcn_exp2f(x);
#else
    return exp2f(x);
#endif
}

// ---------------- fused cvt (all 4 tensors) + prep (rope table, exp2 mask)
__global__ __launch_bounds__(256) void cvt_all_kernel(
    const float* __restrict__ hs, const float* __restrict__ Wq,
    const float* __restrict__ Wk, const float* __restrict__ Wv,
    const float* __restrict__ mask,
    bf16* __restrict__ Xb, bf16* __restrict__ Wqb,
    bf16* __restrict__ Wkb, bf16* __restrict__ Wvb,
    float2* __restrict__ tab, bf16* __restrict__ wM, float* __restrict__ wV) {
    int b = blockIdx.x;
    const float* src; bf16* dst; size_t base;
    if (b < 2048)      { src = hs; dst = Xb;  base = (size_t)b * 2048; }
    else if (b < 2560) { src = Wq; dst = Wqb; base = (size_t)(b - 2048) * 2048; }
    else if (b < 3072) { src = Wk; dst = Wkb; base = (size_t)(b - 2560) * 2048; }
    else               { src = Wv; dst = Wvb; base = (size_t)(b - 3072) * 2048; }
    size_t i = base + threadIdx.x * 8;
    float4 v0 = *reinterpret_cast<const float4*>(src + i);
    float4 v1 = *reinterpret_cast<const float4*>(src + i + 4);
    bf16x8 o;
    o[0] = (bf16)v0.x; o[1] = (bf16)v0.y; o[2] = (bf16)v0.z; o[3] = (bf16)v0.w;
    o[4] = (bf16)v1.x; o[5] = (bf16)v1.y; o[6] = (bf16)v1.z; o[7] = (bf16)v1.w;
    *reinterpret_cast<bf16x8*>(dst + i) = o;

    int idx = b * 256 + threadIdx.x;
    if (idx < S_ * 32) {
        int ii = idx & 31, s = idx >> 5;
        double ang = (double)s * exp(-(double)(2 * ii) / 64.0 * log(10000.0));
        tab[idx] = make_float2((float)cos(ang), (float)sin(ang));
    }
    if (idx < S_) {
        float e = exp2f(mask[idx] * LOG2E);
        bf16 eb = (bf16)e;
        wM[idx] = eb;
        wV[idx] = (float)eb;
    }
}

// ---------------- QKV GEMM + fused RoPE (Q,K) / mask-fold (V) epilogue ----
// This round's single delta: 2-phase double-buffered LDS (stage kt+1 before
// computing kt, ONE barrier per K-tile — r6-attn-proven discipline).
__global__ __launch_bounds__(256) void qkv_gemm_kernel(
    const bf16* __restrict__ Xb,
    const bf16* __restrict__ Wqb, const bf16* __restrict__ Wkb, const bf16* __restrict__ Wvb,
    const float* __restrict__ bqp, const float* __restrict__ bkp, const float* __restrict__ bvp,
    const float2* __restrict__ tab, const float* __restrict__ wV,
    bf16* __restrict__ Qo, bf16* __restrict__ Ko, bf16* __restrict__ Vto)
{
    __shared__ bf16 Alds[2][128 * 64];
    __shared__ bf16 Blds[2][128 * 64];
    const int z = blockIdx.z;
    const bf16* W = z == 0 ? Wqb : z == 1 ? Wkb : Wvb;
    const float* bias = z == 0 ? bqp : z == 1 ? bkp : bvp;
    const int tm = blockIdx.y * 128, tn = blockIdx.x * 128;
    const int tid = threadIdx.x, lane = tid & 63, wid = tid >> 6;
    const int wm = (wid >> 1) * 64, wn = (wid & 1) * 64;
    const int lr = lane & 15, lg = lane >> 4;
    const int c_row = tid >> 3, c_sub = tid & 7;

    f32x4 acc[4][4] = {};

    auto STAGE_G = [&](int buf, int kt) {   // kt = element offset in K dim
        #pragma unroll
        for (int is = 0; is < 4; ++is) {
            int row = is * 32 + c_row;
            int sub = c_sub ^ (row & 7);
            gload16(&Xb[(size_t)(tm + row) * H_ + kt + sub * 8],
                    &Alds[buf][(is * 256 + wid * 64) * 8]);
            gload16(&W[(size_t)(tn + row) * H_ + kt + sub * 8],
                    &Blds[buf][(is * 256 + wid * 64) * 8]);
        }
    };

    STAGE_G(0, 0);
    __syncthreads();
    int buf = 0;

    for (int kt = 0; kt < H_; kt += 64) {
        if (kt + 64 < H_) STAGE_G(buf ^ 1, kt + 64);

        #pragma unroll
        for (int kc = 0; kc < 2; ++kc) {
            bf16x8 af[4], bfr[4];
            #pragma unroll
            for (int mb = 0; mb < 4; ++mb) {
                int row = wm + mb * 16 + lr;
                int ch = (kc * 4 + lg) ^ (row & 7);
                af[mb] = *reinterpret_cast<const bf16x8*>(&Alds[buf][row * 64 + ch * 8]);
            }
            #pragma unroll
            for (int nb = 0; nb < 4; ++nb) {
                int row = wn + nb * 16 + lr;
                int ch = (kc * 4 + lg) ^ (row & 7);
                bfr[nb] = *reinterpret_cast<const bf16x8*>(&Blds[buf][row * 64 + ch * 8]);
            }
            __builtin_amdgcn_s_setprio(1);
            #pragma unroll
            for (int mb = 0; mb < 4; ++mb)
                #pragma unroll
                for (int nb = 0; nb < 4; ++nb)
                    acc[mb][nb] = mfma16(af[mb], bfr[nb], acc[mb][nb]);
            __builtin_amdgcn_s_setprio(0);
        }
        __syncthreads();   // drains staged loads for buf^1; buf reads done
        buf ^= 1;
    }

    float bv4[4];
    #pragma unroll
    for (int nb = 0; nb < 4; ++nb) bv4[nb] = bias[tn + wn + nb * 16 + lr];

    if (z < 2) {
        bf16* Y = z == 0 ? Qo : Ko;
        const float fs = z == 0 ? QSCALE : 1.0f;
        #pragma unroll
        for (int mb = 0; mb < 4; ++mb) {
            #pragma unroll
            for (int r = 0; r < 4; ++r) {
                int row = tm + wm + mb * 16 + lg * 4 + r;
                #pragma unroll
                for (int nb = 0; nb < 2; ++nb) {
                    float2 cs = tab[row * 32 + nb * 16 + lr];
                    float x1 = acc[mb][nb][r] + bv4[nb];
                    float x2 = acc[mb][nb + 2][r] + bv4[nb + 2];
                    int col = tn + wn + nb * 16 + lr;
                    Y[(size_t)row * H_ + col]      = (bf16)((x1 * cs.x - x2 * cs.y) * fs);
                    Y[(size_t)row * H_ + col + 32] = (bf16)((x2 * cs.x + x1 * cs.y) * fs);
                }
            }
        }
    } else {
        #pragma unroll
        for (int mb = 0; mb < 4; ++mb) {
            int rowb = tm + wm + mb * 16 + lg * 4;   // key index base
            float4 wv = *reinterpret_cast<const float4*>(&wV[rowb]);
            float wvr[4] = {wv.x, wv.y, wv.z, wv.w};
            #pragma unroll
            for (int nb = 0; nb < 4; ++nb) {
                int col = tn + wn + nb * 16 + lr;
                bf16x4 pk;
                #pragma unroll
                for (int r = 0; r < 4; ++r)
                    pk[r] = (bf16)((acc[mb][nb][r] + bv4[nb]) * wvr[r]);
                *reinterpret_cast<bf16x4*>(&Vto[(size_t)col * S_ + rowb]) = pk;
            }
        }
    }
}

// ---------------- Flash attention: split-KV + XCD swizzle (r17-proven) ----
template<int NSPLIT>
__global__ __launch_bounds__(256, 4) void attn_kernel(
    const bf16* __restrict__ Q, const bf16* __restrict__ K, const bf16* __restrict__ Vt,
    const bf16* __restrict__ wM, float* __restrict__ out,
    float* __restrict__ opart, float* __restrict__ lpart)
{
    __shared__ bf16 Kl[2][64 * 64];
    __shared__ bf16 Vl[2][64 * 64];
    int x, h, z;
    if (NSPLIT == 2) {
        int lin = blockIdx.x;                 // 1024 blocks, 1D
        int xcd = lin & 7, j = lin >> 3;      // id%8 -> XCD (default round-robin)
        int pair = xcd + 8 * (j >> 5);        // 4 (h,z) pairs per XCD
        x = j & 31;
        h = pair & 15;
        z = pair >> 4;
    } else {
        x = blockIdx.x;
        h = blockIdx.y;
        z = 0;
    }
    const int qb = x * 128;
    const int tid = threadIdx.x, lane = tid & 63, wid = tid >> 6;
    const int l31 = lane & 31, hi = lane >> 5;
    const int srow = wid * 8 + (lane >> 3);   // staging row (within 32-row group)
    const int ssub = (lane & 7) ^ (srow & 7); // swizzled chunk; (row+32)&7 == row&7

    const int NT = S_ / 64;
    const int t0 = z * (NT / NSPLIT), t1 = t0 + NT / NSPLIT;

    bf16x8 qf[4];
    {
        const bf16* qp = &Q[(size_t)(qb + wid * 32 + l31) * H_ + h * 64 + hi * 8];
        #pragma unroll
        for (int ks = 0; ks < 4; ++ks)
            qf[ks] = *reinterpret_cast<const bf16x8*>(qp + ks * 16);
    }

    f32x16 o0 = {}, o1 = {}, lacc = {};

    // running staging pointers, starting at tile t0
    const bf16* kg = &K[(size_t)(t0 * 64 + srow) * H_ + h * 64 + ssub * 8];
    const bf16* vg = &Vt[(size_t)(h * 64 + srow) * S_ + t0 * 64 + ssub * 8];

    auto STAGE = [&](int buf) {
        gload16(kg,           &Kl[buf][(wid * 8) * 64]);
        gload16(kg + 32 * H_, &Kl[buf][(32 + wid * 8) * 64]);
        gload16(vg,           &Vl[buf][(wid * 8) * 64]);
        gload16(vg + 32 * S_, &Vl[buf][(32 + wid * 8) * 64]);
        kg += 64 * H_;
        vg += 64;
    };

    STAGE(0);
    __syncthreads();
    int cur = 0;
    const bf16* wmt = wM + t0 * 64 + hi * 8;

    for (int t = t0; t < t1; ++t) {
        if (t + 1 < t1) STAGE(cur ^ 1);

        // ---- QK(t), serial ----
        f32x16 sc0 = {}, sc1 = {};
        const bf16* Kb_ = Kl[cur];
        __builtin_amdgcn_s_setprio(1);
        #pragma unroll
        for (int ks = 0; ks < 4; ++ks) {
            int ch = (2 * ks + hi) ^ (l31 & 7);
            bf16x8 kf0 = *reinterpret_cast<const bf16x8*>(&Kb_[l31 * 64 + ch * 8]);
            sc0 = mfma32(kf0, qf[ks], sc0);
            bf16x8 kf1 = *reinterpret_cast<const bf16x8*>(&Kb_[(32 + l31) * 64 + ch * 8]);
            sc1 = mfma32(kf1, qf[ks], sc1);
        }
        __builtin_amdgcn_s_setprio(0);

        // ---- softmax(t): p = exp2(score) in place (no mask, no max) ----
        #pragma unroll
        for (int r = 0; r < 16; ++r) sc0[r] = fexp2(sc0[r]);
        #pragma unroll
        for (int r = 0; r < 16; ++r) sc1[r] = fexp2(sc1[r]);

        // ---- P -> PV B-fragments (cvt_pk + permlane32_swap) ----
        bf16x8 pf[4];
        #pragma unroll
        for (int ks = 0; ks < 2; ++ks) {
            unsigned w[4];
            #pragma unroll
            for (int wi = 0; wi < 2; ++wi) {
                unsigned u = cvtpk(sc0[8 * ks + 2 * wi],     sc0[8 * ks + 2 * wi + 1]);
                unsigned v = cvtpk(sc0[8 * ks + 4 + 2 * wi], sc0[8 * ks + 4 + 2 * wi + 1]);
                swap32(u, v, w[wi], w[wi + 2]);
            }
            union { unsigned u[4]; bf16x8 v; } cv;
            cv.u[0] = w[0]; cv.u[1] = w[1]; cv.u[2] = w[2]; cv.u[3] = w[3];
            pf[ks] = cv.v;
        }
        #pragma unroll
        for (int ks = 0; ks < 2; ++ks) {
            unsigned w[4];
            #pragma unroll
            for (int wi = 0; wi < 2; ++wi) {
                unsigned u = cvtpk(sc1[8 * ks + 2 * wi],     sc1[8 * ks + 2 * wi + 1]);
                unsigned v = cvtpk(sc1[8 * ks + 4 + 2 * wi], sc1[8 * ks + 4 + 2 * wi + 1]);
                swap32(u, v, w[wi], w[wi + 2]);
            }
            union { unsigned u[4]; bf16x8 v; } cv;
            cv.u[0] = w[0]; cv.u[1] = w[1]; cv.u[2] = w[2]; cv.u[3] = w[3];
            pf[2 + ks] = cv.v;
        }

        // ---- PV(t) + l(t): O^T += Vt' * P^T ; lacc += wf * P^T ----
        const bf16* Vb_ = Vl[cur];
        __builtin_amdgcn_s_setprio(1);
        #pragma unroll
        for (int ks = 0; ks < 4; ++ks) {
            int ch = (2 * ks + hi) ^ (l31 & 7);
            bf16x8 vf0 = *reinterpret_cast<const bf16x8*>(&Vb_[l31 * 64 + ch * 8]);
            o0 = mfma32(vf0, pf[ks], o0);
            bf16x8 vf1 = *reinterpret_cast<const bf16x8*>(&Vb_[(32 + l31) * 64 + ch * 8]);
            o1 = mfma32(vf1, pf[ks], o1);
            bf16x8 wf = *reinterpret_cast<const bf16x8*>(wmt + ks * 16);
            lacc = mfma32(wf, pf[ks], lacc);
        }
        __builtin_amdgcn_s_setprio(0);
        wmt += 64;

        __syncthreads();
        cur ^= 1;
    }

    const int q = qb + wid * 32 + l31;
    if (NSPLIT == 1) {
        float inv = 1.f / lacc[0];
        float* orow = &out[(size_t)q * H_ + h * 64];
        #pragma unroll
        for (int g2 = 0; g2 < 4; ++g2) {
            float4 a, b;
            a.x = o0[g2 * 4 + 0] * inv; a.y = o0[g2 * 4 + 1] * inv;
            a.z = o0[g2 * 4 + 2] * inv; a.w = o0[g2 * 4 + 3] * inv;
            b.x = o1[g2 * 4 + 0] * inv; b.y = o1[g2 * 4 + 1] * inv;
            b.z = o1[g2 * 4 + 2] * inv; b.w = o1[g2 * 4 + 3] * inv;
            *reinterpret_cast<float4*>(orow + 8 * g2 + 4 * hi) = a;
            *reinterpret_cast<float4*>(orow + 32 + 8 * g2 + 4 * hi) = b;
        }
    } else {
        float* op = &opart[(((size_t)z * NH_ + h) * S_ + q) * 64];
        #pragma unroll
        for (int g2 = 0; g2 < 4; ++g2) {
            float4 a, b;
            a.x = o0[g2 * 4 + 0]; a.y = o0[g2 * 4 + 1];
            a.z = o0[g2 * 4 + 2]; a.w = o0[g2 * 4 + 3];
            b.x = o1[g2 * 4 + 0]; b.y = o1[g2 * 4 + 1];
            b.z = o1[g2 * 4 + 2]; b.w = o1[g2 * 4 + 3];
            *reinterpret_cast<float4*>(op + 8 * g2 + 4 * hi) = a;
            *reinterpret_cast<float4*>(op + 32 + 8 * g2 + 4 * hi) = b;
        }
        if (hi == 0)
            lpart[((size_t)z * NH_ + h) * S_ + q] = lacc[0];
    }
}

// ---------------- combine the two KV-half partials (fixed-max: just sums) -
__global__ __launch_bounds__(256) void combine_kernel(const float* __restrict__ opart,
                                                      const float* __restrict__ lpart,
                                                      float* __restrict__ out) {
    int idx = blockIdx.x * 256 + threadIdx.x;   // 2^20 threads, float4 each
    int d4 = idx & 15;
    int q = (idx >> 4) & 4095;
    int h = idx >> 16;
    float l0 = lpart[(size_t)h * S_ + q];
    float l1 = lpart[((size_t)NH_ + h) * S_ + q];
    float inv = 1.f / (l0 + l1);
    float4 a = *reinterpret_cast<const float4*>(&opart[(((size_t)h) * S_ + q) * 64 + d4 * 4]);
    float4 b = *reinterpret_cast<const float4*>(&opart[(((size_t)NH_ + h) * S_ + q) * 64 + d4 * 4]);
    float4 r;
    r.x = (a.x + b.x) * inv;
    r.y = (a.y + b.y) * inv;
    r.z = (a.z + b.z) * inv;
    r.w = (a.w + b.w) * inv;
    *reinterpret_cast<float4*>(&out[(size_t)q * H_ + h * 64 + d4 * 4]) = r;
}

extern "C" void kernel_launch(void* const* d_in, const int* in_sizes, int n_in,
                              void* d_out, int out_size, void* d_ws, size_t ws_size,
                              hipStream_t stream) {
    const float* hs   = (const float*)d_in[0];
    const float* mask = (const float*)d_in[1];
    const float* Wq   = (const float*)d_in[2];
    const float* bq   = (const float*)d_in[3];
    const float* Wk   = (const float*)d_in[4];
    const float* bk   = (const float*)d_in[5];
    const float* Wv   = (const float*)d_in[6];
    const float* bv   = (const float*)d_in[7];
    float* out = (float*)d_out;

    char* ws = (char*)d_ws;
    bf16* Xb    = (bf16*)(ws);                  // 8 MB  [S,H]
    bf16* Wqb   = (bf16*)(ws + (8u  << 20));    // 2 MB
    bf16* Wkb   = (bf16*)(ws + (10u << 20));    // 2 MB
    bf16* Wvb   = (bf16*)(ws + (12u << 20));    // 2 MB
    bf16* Qb    = (bf16*)(ws + (14u << 20));    // 8 MB  [S,H]
    bf16* Kb    = (bf16*)(ws + (22u << 20));    // 8 MB  [S,H]
    bf16* Vt    = (bf16*)(ws + (30u << 20));    // 8 MB  [H,S]
    float2* tab = (float2*)(ws + (38u << 20));  // 1 MB  [S,32]
    bf16* wM    = (bf16*)(ws + (39u << 20));    // 8 KB  exp2-mask bf16
    float* wV   = (float*)(ws + (39u << 20) + 65536); // 16 KB exp2-mask f32
    float* opart = (float*)(ws + (40u << 20));  // 32 MB [2][NH][S][64]
    float* lpart = (float*)(ws + (72u << 20));  // 512 KB [2][NH][S]
    const size_t NEED = (size_t)73u << 20;

    cvt_all_kernel<<<3584, 256, 0, stream>>>(hs, Wq, Wk, Wv, mask,
                                             Xb, Wqb, Wkb, Wvb, tab, wM, wV);
    qkv_gemm_kernel<<<dim3(H_ / 128, S_ / 128, 3), 256, 0, stream>>>(
        Xb, Wqb, Wkb, Wvb, bq, bk, bv, tab, wV, Qb, Kb, Vt);

    if (ws_size >= NEED) {
        attn_kernel<2><<<1024, 256, 0, stream>>>(
            Qb, Kb, Vt, wM, out, opart, lpart);
        combine_kernel<<<(S_ * NH_ * 16) / 256, 256, 0, stream>>>(opart, lpart, out);
    } else {
        attn_kernel<1><<<dim3(S_ / 128, NH_, 1), 256, 0, stream>>>(
            Qb, Kb, Vt, wM, out, nullptr, nullptr);
    }
}

// Round 19
// 137.318 us; speedup vs baseline: 2.5011x; 1.0300x over previous
//
#include <hip/hip_runtime.h>
#include <hip/hip_bf16.h>
#include <math.h>
#include <stdint.h>

#define S_ 4096
#define H_ 1024
#define NH_ 16
#define HD_ 64
#define LOG2E 1.4426950408889634f
#define QSCALE (0.125f * LOG2E)

typedef __bf16 bf16;
typedef __attribute__((ext_vector_type(8))) __bf16 bf16x8;
typedef __attribute__((ext_vector_type(4))) __bf16 bf16x4;
typedef __attribute__((ext_vector_type(4))) float f32x4;
typedef __attribute__((ext_vector_type(16))) float f32x16;
typedef __attribute__((ext_vector_type(2))) float f32x2;
typedef __attribute__((ext_vector_type(2))) int int2v;

__device__ __forceinline__ f32x4 mfma16(bf16x8 a, bf16x8 b, f32x4 c) {
    return __builtin_amdgcn_mfma_f32_16x16x32_bf16(a, b, c, 0, 0, 0);
}
__device__ __forceinline__ f32x16 mfma32(bf16x8 a, bf16x8 b, f32x16 c) {
    return __builtin_amdgcn_mfma_f32_32x32x16_bf16(a, b, c, 0, 0, 0);
}

// async global->LDS, 16B per lane; LDS dest = wave-uniform base + lane*16.
__device__ __forceinline__ void gload16(const void* g, void* l) {
    __builtin_amdgcn_global_load_lds(
        (__attribute__((address_space(1))) void*)(uintptr_t)g,
        (__attribute__((address_space(3))) void*)(uintptr_t)l,
        16, 0, 0);
}

// pack two f32 -> one u32 of 2 bf16 (lo = a, hi = b) — proven r2
__device__ __forceinline__ unsigned cvtpk(float a, float b) {
    unsigned r;
    asm("v_cvt_pk_bf16_f32 %0, %1, %2" : "=v"(r) : "v"(a), "v"(b));
    return r;
}

// proven r2 half-wave exchange
__device__ __forceinline__ void swap32(unsigned a, unsigned b, unsigned& r0, unsigned& r1) {
#if __has_builtin(__builtin_amdgcn_permlane32_swap)
    int2v rr = __builtin_amdgcn_permlane32_swap((int)a, (int)b, false, false);
    r0 = (unsigned)rr[0];
    r1 = (unsigned)rr[1];
#else
    unsigned sa = (unsigned)__shfl_xor((int)a, 32, 64);
    unsigned sb = (unsigned)__shfl_xor((int)b, 32, 64);
    bool hi = (threadIdx.x & 32) != 0;
    r0 = hi ? sb : a;
    r1 = hi ? b : sa;
#endif
}

// raw hardware exp2: 1 instr (v_exp_f32). Inputs bounded ~|4| here.
__device__ __forceinline__ float fexp2(float x) {
#if __has_builtin(__builtin_amdgcn_exp2f)
    return __builtin_amdgcn_exp2f(x);
#else
    return exp2f(x);
#endif
}

// ---------------- fused cvt (all 4 tensors) + prep (rope table, exp2 mask)
__global__ __launch_bounds__(256) void cvt_all_kernel(
    const float* __restrict__ hs, const float* __restrict__ Wq,
    const float* __restrict__ Wk, const float* __restrict__ Wv,
    const float* __restrict__ mask,
    bf16* __restrict__ Xb, bf16* __restrict__ Wqb,
    bf16* __restrict__ Wkb, bf16* __restrict__ Wvb,
    float2* __restrict__ tab, bf16* __restrict__ wM, float* __restrict__ wV) {
    int b = blockIdx.x;
    const float* src; bf16* dst; size_t base;
    if (b < 2048)      { src = hs; dst = Xb;  base = (size_t)b * 2048; }
    else if (b < 2560) { src = Wq; dst = Wqb; base = (size_t)(b - 2048) * 2048; }
    else if (b < 3072) { src = Wk; dst = Wkb; base = (size_t)(b - 2560) * 2048; }
    else               { src = Wv; dst = Wvb; base = (size_t)(b - 3072) * 2048; }
    size_t i = base + threadIdx.x * 8;
    float4 v0 = *reinterpret_cast<const float4*>(src + i);
    float4 v1 = *reinterpret_cast<const float4*>(src + i + 4);
    bf16x8 o;
    o[0] = (bf16)v0.x; o[1] = (bf16)v0.y; o[2] = (bf16)v0.z; o[3] = (bf16)v0.w;
    o[4] = (bf16)v1.x; o[5] = (bf16)v1.y; o[6] = (bf16)v1.z; o[7] = (bf16)v1.w;
    *reinterpret_cast<bf16x8*>(dst + i) = o;

    int idx = b * 256 + threadIdx.x;
    if (idx < S_ * 32) {
        int ii = idx & 31, s = idx >> 5;
        double ang = (double)s * exp(-(double)(2 * ii) / 64.0 * log(10000.0));
        tab[idx] = make_float2((float)cos(ang), (float)sin(ang));
    }
    if (idx < S_) {
        float e = exp2f(mask[idx] * LOG2E);
        bf16 eb = (bf16)e;
        wM[idx] = eb;
        wV[idx] = (float)eb;
    }
}

// ---------------- QKV GEMM + fused RoPE (Q,K) / mask-fold (V) epilogue ----
// (r18-proven: 2-phase double-buffered LDS, one barrier per K-tile)
__global__ __launch_bounds__(256) void qkv_gemm_kernel(
    const bf16* __restrict__ Xb,
    const bf16* __restrict__ Wqb, const bf16* __restrict__ Wkb, const bf16* __restrict__ Wvb,
    const float* __restrict__ bqp, const float* __restrict__ bkp, const float* __restrict__ bvp,
    const float2* __restrict__ tab, const float* __restrict__ wV,
    bf16* __restrict__ Qo, bf16* __restrict__ Ko, bf16* __restrict__ Vto)
{
    __shared__ bf16 Alds[2][128 * 64];
    __shared__ bf16 Blds[2][128 * 64];
    const int z = blockIdx.z;
    const bf16* W = z == 0 ? Wqb : z == 1 ? Wkb : Wvb;
    const float* bias = z == 0 ? bqp : z == 1 ? bkp : bvp;
    const int tm = blockIdx.y * 128, tn = blockIdx.x * 128;
    const int tid = threadIdx.x, lane = tid & 63, wid = tid >> 6;
    const int wm = (wid >> 1) * 64, wn = (wid & 1) * 64;
    const int lr = lane & 15, lg = lane >> 4;
    const int c_row = tid >> 3, c_sub = tid & 7;

    f32x4 acc[4][4] = {};

    auto STAGE_G = [&](int buf, int kt) {
        #pragma unroll
        for (int is = 0; is < 4; ++is) {
            int row = is * 32 + c_row;
            int sub = c_sub ^ (row & 7);
            gload16(&Xb[(size_t)(tm + row) * H_ + kt + sub * 8],
                    &Alds[buf][(is * 256 + wid * 64) * 8]);
            gload16(&W[(size_t)(tn + row) * H_ + kt + sub * 8],
                    &Blds[buf][(is * 256 + wid * 64) * 8]);
        }
    };

    STAGE_G(0, 0);
    __syncthreads();
    int buf = 0;

    for (int kt = 0; kt < H_; kt += 64) {
        if (kt + 64 < H_) STAGE_G(buf ^ 1, kt + 64);

        #pragma unroll
        for (int kc = 0; kc < 2; ++kc) {
            bf16x8 af[4], bfr[4];
            #pragma unroll
            for (int mb = 0; mb < 4; ++mb) {
                int row = wm + mb * 16 + lr;
                int ch = (kc * 4 + lg) ^ (row & 7);
                af[mb] = *reinterpret_cast<const bf16x8*>(&Alds[buf][row * 64 + ch * 8]);
            }
            #pragma unroll
            for (int nb = 0; nb < 4; ++nb) {
                int row = wn + nb * 16 + lr;
                int ch = (kc * 4 + lg) ^ (row & 7);
                bfr[nb] = *reinterpret_cast<const bf16x8*>(&Blds[buf][row * 64 + ch * 8]);
            }
            __builtin_amdgcn_s_setprio(1);
            #pragma unroll
            for (int mb = 0; mb < 4; ++mb)
                #pragma unroll
                for (int nb = 0; nb < 4; ++nb)
                    acc[mb][nb] = mfma16(af[mb], bfr[nb], acc[mb][nb]);
            __builtin_amdgcn_s_setprio(0);
        }
        __syncthreads();
        buf ^= 1;
    }

    float bv4[4];
    #pragma unroll
    for (int nb = 0; nb < 4; ++nb) bv4[nb] = bias[tn + wn + nb * 16 + lr];

    if (z < 2) {
        bf16* Y = z == 0 ? Qo : Ko;
        const float fs = z == 0 ? QSCALE : 1.0f;
        #pragma unroll
        for (int mb = 0; mb < 4; ++mb) {
            #pragma unroll
            for (int r = 0; r < 4; ++r) {
                int row = tm + wm + mb * 16 + lg * 4 + r;
                #pragma unroll
                for (int nb = 0; nb < 2; ++nb) {
                    float2 cs = tab[row * 32 + nb * 16 + lr];
                    float x1 = acc[mb][nb][r] + bv4[nb];
                    float x2 = acc[mb][nb + 2][r] + bv4[nb + 2];
                    int col = tn + wn + nb * 16 + lr;
                    Y[(size_t)row * H_ + col]      = (bf16)((x1 * cs.x - x2 * cs.y) * fs);
                    Y[(size_t)row * H_ + col + 32] = (bf16)((x2 * cs.x + x1 * cs.y) * fs);
                }
            }
        }
    } else {
        #pragma unroll
        for (int mb = 0; mb < 4; ++mb) {
            int rowb = tm + wm + mb * 16 + lg * 4;   // key index base
            float4 wv = *reinterpret_cast<const float4*>(&wV[rowb]);
            float wvr[4] = {wv.x, wv.y, wv.z, wv.w};
            #pragma unroll
            for (int nb = 0; nb < 4; ++nb) {
                int col = tn + wn + nb * 16 + lr;
                bf16x4 pk;
                #pragma unroll
                for (int r = 0; r < 4; ++r)
                    pk[r] = (bf16)((acc[mb][nb][r] + bv4[nb]) * wvr[r]);
                *reinterpret_cast<bf16x4*>(&Vto[(size_t)col * S_ + rowb]) = pk;
            }
        }
    }
}

// ---------------- Flash attention: split-KV + XCD swizzle (r17-proven) ----
// This round's delta: NSPLIT=2 partials stored as bf16 (halves partial
// write + combine read traffic; |out|<~0.1 so bf16 rel err 2^-9 adds only
// ~2e-4 absolute — 4x under threshold).
template<int NSPLIT>
__global__ __launch_bounds__(256, 4) void attn_kernel(
    const bf16* __restrict__ Q, const bf16* __restrict__ K, const bf16* __restrict__ Vt,
    const bf16* __restrict__ wM, float* __restrict__ out,
    bf16* __restrict__ opart, float* __restrict__ lpart)
{
    __shared__ bf16 Kl[2][64 * 64];
    __shared__ bf16 Vl[2][64 * 64];
    int x, h, z;
    if (NSPLIT == 2) {
        int lin = blockIdx.x;                 // 1024 blocks, 1D
        int xcd = lin & 7, j = lin >> 3;      // id%8 -> XCD (default round-robin)
        int pair = xcd + 8 * (j >> 5);        // 4 (h,z) pairs per XCD
        x = j & 31;
        h = pair & 15;
        z = pair >> 4;
    } else {
        x = blockIdx.x;
        h = blockIdx.y;
        z = 0;
    }
    const int qb = x * 128;
    const int tid = threadIdx.x, lane = tid & 63, wid = tid >> 6;
    const int l31 = lane & 31, hi = lane >> 5;
    const int srow = wid * 8 + (lane >> 3);   // staging row (within 32-row group)
    const int ssub = (lane & 7) ^ (srow & 7); // swizzled chunk; (row+32)&7 == row&7

    const int NT = S_ / 64;
    const int t0 = z * (NT / NSPLIT), t1 = t0 + NT / NSPLIT;

    bf16x8 qf[4];
    {
        const bf16* qp = &Q[(size_t)(qb + wid * 32 + l31) * H_ + h * 64 + hi * 8];
        #pragma unroll
        for (int ks = 0; ks < 4; ++ks)
            qf[ks] = *reinterpret_cast<const bf16x8*>(qp + ks * 16);
    }

    f32x16 o0 = {}, o1 = {}, lacc = {};

    // running staging pointers, starting at tile t0
    const bf16* kg = &K[(size_t)(t0 * 64 + srow) * H_ + h * 64 + ssub * 8];
    const bf16* vg = &Vt[(size_t)(h * 64 + srow) * S_ + t0 * 64 + ssub * 8];

    auto STAGE = [&](int buf) {
        gload16(kg,           &Kl[buf][(wid * 8) * 64]);
        gload16(kg + 32 * H_, &Kl[buf][(32 + wid * 8) * 64]);
        gload16(vg,           &Vl[buf][(wid * 8) * 64]);
        gload16(vg + 32 * S_, &Vl[buf][(32 + wid * 8) * 64]);
        kg += 64 * H_;
        vg += 64;
    };

    STAGE(0);
    __syncthreads();
    int cur = 0;
    const bf16* wmt = wM + t0 * 64 + hi * 8;

    for (int t = t0; t < t1; ++t) {
        if (t + 1 < t1) STAGE(cur ^ 1);

        // ---- QK(t), serial ----
        f32x16 sc0 = {}, sc1 = {};
        const bf16* Kb_ = Kl[cur];
        __builtin_amdgcn_s_setprio(1);
        #pragma unroll
        for (int ks = 0; ks < 4; ++ks) {
            int ch = (2 * ks + hi) ^ (l31 & 7);
            bf16x8 kf0 = *reinterpret_cast<const bf16x8*>(&Kb_[l31 * 64 + ch * 8]);
            sc0 = mfma32(kf0, qf[ks], sc0);
            bf16x8 kf1 = *reinterpret_cast<const bf16x8*>(&Kb_[(32 + l31) * 64 + ch * 8]);
            sc1 = mfma32(kf1, qf[ks], sc1);
        }
        __builtin_amdgcn_s_setprio(0);

        // ---- softmax(t): p = exp2(score) in place (no mask, no max) ----
        #pragma unroll
        for (int r = 0; r < 16; ++r) sc0[r] = fexp2(sc0[r]);
        #pragma unroll
        for (int r = 0; r < 16; ++r) sc1[r] = fexp2(sc1[r]);

        // ---- P -> PV B-fragments (cvt_pk + permlane32_swap) ----
        bf16x8 pf[4];
        #pragma unroll
        for (int ks = 0; ks < 2; ++ks) {
            unsigned w[4];
            #pragma unroll
            for (int wi = 0; wi < 2; ++wi) {
                unsigned u = cvtpk(sc0[8 * ks + 2 * wi],     sc0[8 * ks + 2 * wi + 1]);
                unsigned v = cvtpk(sc0[8 * ks + 4 + 2 * wi], sc0[8 * ks + 4 + 2 * wi + 1]);
                swap32(u, v, w[wi], w[wi + 2]);
            }
            union { unsigned u[4]; bf16x8 v; } cv;
            cv.u[0] = w[0]; cv.u[1] = w[1]; cv.u[2] = w[2]; cv.u[3] = w[3];
            pf[ks] = cv.v;
        }
        #pragma unroll
        for (int ks = 0; ks < 2; ++ks) {
            unsigned w[4];
            #pragma unroll
            for (int wi = 0; wi < 2; ++wi) {
                unsigned u = cvtpk(sc1[8 * ks + 2 * wi],     sc1[8 * ks + 2 * wi + 1]);
                unsigned v = cvtpk(sc1[8 * ks + 4 + 2 * wi], sc1[8 * ks + 4 + 2 * wi + 1]);
                swap32(u, v, w[wi], w[wi + 2]);
            }
            union { unsigned u[4]; bf16x8 v; } cv;
            cv.u[0] = w[0]; cv.u[1] = w[1]; cv.u[2] = w[2]; cv.u[3] = w[3];
            pf[2 + ks] = cv.v;
        }

        // ---- PV(t) + l(t): O^T += Vt' * P^T ; lacc += wf * P^T ----
        const bf16* Vb_ = Vl[cur];
        __builtin_amdgcn_s_setprio(1);
        #pragma unroll
        for (int ks = 0; ks < 4; ++ks) {
            int ch = (2 * ks + hi) ^ (l31 & 7);
            bf16x8 vf0 = *reinterpret_cast<const bf16x8*>(&Vb_[l31 * 64 + ch * 8]);
            o0 = mfma32(vf0, pf[ks], o0);
            bf16x8 vf1 = *reinterpret_cast<const bf16x8*>(&Vb_[(32 + l31) * 64 + ch * 8]);
            o1 = mfma32(vf1, pf[ks], o1);
            bf16x8 wf = *reinterpret_cast<const bf16x8*>(wmt + ks * 16);
            lacc = mfma32(wf, pf[ks], lacc);
        }
        __builtin_amdgcn_s_setprio(0);
        wmt += 64;

        __syncthreads();
        cur ^= 1;
    }

    const int q = qb + wid * 32 + l31;
    if (NSPLIT == 1) {
        float inv = 1.f / lacc[0];
        float* orow = &out[(size_t)q * H_ + h * 64];
        #pragma unroll
        for (int g2 = 0; g2 < 4; ++g2) {
            float4 a, b;
            a.x = o0[g2 * 4 + 0] * inv; a.y = o0[g2 * 4 + 1] * inv;
            a.z = o0[g2 * 4 + 2] * inv; a.w = o0[g2 * 4 + 3] * inv;
            b.x = o1[g2 * 4 + 0] * inv; b.y = o1[g2 * 4 + 1] * inv;
            b.z = o1[g2 * 4 + 2] * inv; b.w = o1[g2 * 4 + 3] * inv;
            *reinterpret_cast<float4*>(orow + 8 * g2 + 4 * hi) = a;
            *reinterpret_cast<float4*>(orow + 32 + 8 * g2 + 4 * hi) = b;
        }
    } else {
        // partials in bf16 (halves store+combine traffic)
        bf16* op = &opart[(((size_t)z * NH_ + h) * S_ + q) * 64];
        #pragma unroll
        for (int g2 = 0; g2 < 4; ++g2) {
            bf16x4 a, b;
            #pragma unroll
            for (int j = 0; j < 4; ++j) {
                a[j] = (bf16)o0[g2 * 4 + j];
                b[j] = (bf16)o1[g2 * 4 + j];
            }
            *reinterpret_cast<bf16x4*>(op + 8 * g2 + 4 * hi) = a;
            *reinterpret_cast<bf16x4*>(op + 32 + 8 * g2 + 4 * hi) = b;
        }
        if (hi == 0)
            lpart[((size_t)z * NH_ + h) * S_ + q] = lacc[0];
    }
}

// ---------------- combine the two KV-half partials (fixed-max: just sums) -
__global__ __launch_bounds__(256) void combine_kernel(const bf16* __restrict__ opart,
                                                      const float* __restrict__ lpart,
                                                      float* __restrict__ out) {
    int idx = blockIdx.x * 256 + threadIdx.x;   // 2^20 threads, 4 elems each
    int d4 = idx & 15;
    int q = (idx >> 4) & 4095;
    int h = idx >> 16;
    float l0 = lpart[(size_t)h * S_ + q];
    float l1 = lpart[((size_t)NH_ + h) * S_ + q];
    float inv = 1.f / (l0 + l1);
    bf16x4 a = *reinterpret_cast<const bf16x4*>(&opart[(((size_t)h) * S_ + q) * 64 + d4 * 4]);
    bf16x4 b = *reinterpret_cast<const bf16x4*>(&opart[(((size_t)NH_ + h) * S_ + q) * 64 + d4 * 4]);
    float4 r;
    r.x = ((float)a[0] + (float)b[0]) * inv;
    r.y = ((float)a[1] + (float)b[1]) * inv;
    r.z = ((float)a[2] + (float)b[2]) * inv;
    r.w = ((float)a[3] + (float)b[3]) * inv;
    *reinterpret_cast<float4*>(&out[(size_t)q * H_ + h * 64 + d4 * 4]) = r;
}

extern "C" void kernel_launch(void* const* d_in, const int* in_sizes, int n_in,
                              void* d_out, int out_size, void* d_ws, size_t ws_size,
                              hipStream_t stream) {
    const float* hs   = (const float*)d_in[0];
    const float* mask = (const float*)d_in[1];
    const float* Wq   = (const float*)d_in[2];
    const float* bq   = (const float*)d_in[3];
    const float* Wk   = (const float*)d_in[4];
    const float* bk   = (const float*)d_in[5];
    const float* Wv   = (const float*)d_in[6];
    const float* bv   = (const float*)d_in[7];
    float* out = (float*)d_out;

    char* ws = (char*)d_ws;
    bf16* Xb    = (bf16*)(ws);                  // 8 MB  [S,H]
    bf16* Wqb   = (bf16*)(ws + (8u  << 20));    // 2 MB
    bf16* Wkb   = (bf16*)(ws + (10u << 20));    // 2 MB
    bf16* Wvb   = (bf16*)(ws + (12u << 20));    // 2 MB
    bf16* Qb    = (bf16*)(ws + (14u << 20));    // 8 MB  [S,H]
    bf16* Kb    = (bf16*)(ws + (22u << 20));    // 8 MB  [S,H]
    bf16* Vt    = (bf16*)(ws + (30u << 20));    // 8 MB  [H,S]
    float2* tab = (float2*)(ws + (38u << 20));  // 1 MB  [S,32]
    bf16* wM    = (bf16*)(ws + (39u << 20));    // 8 KB  exp2-mask bf16
    float* wV   = (float*)(ws + (39u << 20) + 65536); // 16 KB exp2-mask f32
    bf16* opart = (bf16*)(ws + (40u << 20));    // 16 MB [2][NH][S][64] bf16
    float* lpart = (float*)(ws + (56u << 20));  // 512 KB [2][NH][S]
    const size_t NEED = (size_t)57u << 20;

    cvt_all_kernel<<<3584, 256, 0, stream>>>(hs, Wq, Wk, Wv, mask,
                                             Xb, Wqb, Wkb, Wvb, tab, wM, wV);
    qkv_gemm_kernel<<<dim3(H_ / 128, S_ / 128, 3), 256, 0, stream>>>(
        Xb, Wqb, Wkb, Wvb, bq, bk, bv, tab, wV, Qb, Kb, Vt);

    if (ws_size >= NEED) {
        attn_kernel<2><<<1024, 256, 0, stream>>>(
            Qb, Kb, Vt, wM, out, opart, lpart);
        combine_kernel<<<(S_ * NH_ * 16) / 256, 256, 0, stream>>>(opart, lpart, out);
    } else {
        attn_kernel<1><<<dim3(S_ / 128, NH_, 1), 256, 0, stream>>>(
            Qb, Kb, Vt, wM, out, nullptr, nullptr);
    }
}